// Round 4
// baseline (515.625 us; speedup 1.0000x reference)
//
#include <hip/hip_runtime.h>
#include <hip/hip_bf16.h>
#include <stdint.h>

typedef __attribute__((ext_vector_type(8))) __bf16 bf16x8;
typedef __attribute__((ext_vector_type(4))) float floatx4;

#define C 128
#define BROWS 128   // rows per block (2 adjacent 64-row tiles, 8 waves)
#define LSTR 136    // padded bf16 row stride for W: 272 B -> 2 lanes/bank on b128 reads (free)

__device__ __forceinline__ __bf16 f2b(float f) {
  return __builtin_bit_cast(__bf16, __float2bfloat16(f));
}

// histogram of row indices + W fp32 -> bf16 conversion
__global__ void prep_kernel(const int* __restrict__ rowidx, const float* __restrict__ W,
                            int* __restrict__ deg, __bf16* __restrict__ Wb, int n) {
  int i = blockIdx.x * blockDim.x + threadIdx.x;
  if (i < C * C) Wb[i] = f2b(W[i]);
  if (i < n) atomicAdd(deg + rowidx[i], 1);
}

// result[j] = (x[j] + x[col[j]]) @ W.T + 2*b + deg[j]
// ONE-SHOT blocks in hardware dispatch order (R3-verified: keeps gathers
// L3-resident, FETCH/WRITE at the 512MB floor; persistent loops broke this).
// R4 change: 512 threads / 128 rows per block -> 8 waves x 4 blocks/CU
// (LDS-limited) = 32 waves/CU theoretical occupancy, 2x R3's concurrency,
// and W staged once per 128 rows instead of per 64.
__launch_bounds__(512, 8)
__global__ void gconv_kernel(const float* __restrict__ x,
                             const int* __restrict__ colidx,
                             const __bf16* __restrict__ Wb,
                             const float* __restrict__ bias,
                             const int* __restrict__ deg,
                             float* __restrict__ out, int n) {
  __shared__ __bf16 sW[C * LSTR];   // 34816 B

  const int t = threadIdx.x;
  const int lane = t & 63, w = t >> 6;          // w in 0..7
  const int l15 = lane & 15, quad = lane >> 4;

  const int base = blockIdx.x * BROWS + w * 16;

  // issue index/deg loads first -- latency hidden under W staging
  int ga  = base + l15;
  int gal = ga < n ? ga : n - 1;
  int cg  = colidx[gal];

  int gr  = base + quad * 4;
  int grl = (gr + 3 < n) ? gr : ((n - 4) & ~3);
  int4 d4 = *(const int4*)(deg + grl);

  // ---- stage W (bf16, padded rows): thread t covers row t>>2, quarter t&3 ----
  {
    int r = t >> 2, q = t & 3;
    const float4* src = (const float4*)(Wb + r * C + q * 32);
    float4* dst = (float4*)(sW + r * LSTR + q * 32);
#pragma unroll
    for (int i = 0; i < 4; i++) dst[i] = src[i];
  }

  // per-lane bias (col = tt*16 + l15)
  float b2[8];
#pragma unroll
  for (int tt = 0; tt < 8; tt++) b2[tt] = 2.0f * bias[tt * 16 + l15];

  __syncthreads();

  // ---- A-side: 16 float4 loads per lane, straight from global ----
  // lane (l15, quad) owns row base+l15, k = quad*8 + kc*32 + j
  const float4* pa = (const float4*)(x + (size_t)gal * C + quad * 8);
  const float4* pc = (const float4*)(x + (size_t)cg  * C + quad * 8);
  float4 va[8], vc[8];
#pragma unroll
  for (int kc = 0; kc < 4; kc++) {
    va[2 * kc]     = pa[kc * 8];
    va[2 * kc + 1] = pa[kc * 8 + 1];
    vc[2 * kc]     = pc[kc * 8];
    vc[2 * kc + 1] = pc[kc * 8 + 1];
  }

  // B[k = quad*8 + kc*32 + j][ncol = tt*16 + l15] = W[ncol][k]
  const __bf16* bB = sW + l15 * LSTR + quad * 8;

  floatx4 acc[8];
#pragma unroll
  for (int i = 0; i < 8; i++) acc[i] = (floatx4){0.f, 0.f, 0.f, 0.f};

#pragma unroll
  for (int kc = 0; kc < 4; kc++) {
    float4 a0 = va[2 * kc], a1 = va[2 * kc + 1];
    float4 c0 = vc[2 * kc], c1 = vc[2 * kc + 1];
    bf16x8 av;
    av[0] = f2b(a0.x + c0.x); av[1] = f2b(a0.y + c0.y);
    av[2] = f2b(a0.z + c0.z); av[3] = f2b(a0.w + c0.w);
    av[4] = f2b(a1.x + c1.x); av[5] = f2b(a1.y + c1.y);
    av[6] = f2b(a1.z + c1.z); av[7] = f2b(a1.w + c1.w);
#pragma unroll
    for (int tt = 0; tt < 8; tt++) {
      bf16x8 bv = *(const bf16x8*)(bB + tt * 16 * LSTR + kc * 32);
      acc[tt] = __builtin_amdgcn_mfma_f32_16x16x32_bf16(av, bv, acc[tt], 0, 0, 0);
    }
  }

  // ---- epilogue: C/D layout col=l15, row=quad*4+reg (HW-verified) ----
  float dvf[4];
  dvf[0] = (float)d4.x; dvf[1] = (float)d4.y;
  dvf[2] = (float)d4.z; dvf[3] = (float)d4.w;
#pragma unroll
  for (int r = 0; r < 4; r++) {
    int g = gr + r;
    if (g < n) {
      float* orow = out + (size_t)g * C + l15;
      float dv = dvf[r];
#pragma unroll
      for (int tt = 0; tt < 8; tt++) orow[tt * 16] = acc[tt][r] + b2[tt] + dv;
    }
  }
}

extern "C" void kernel_launch(void* const* d_in, const int* in_sizes, int n_in,
                              void* d_out, int out_size, void* d_ws, size_t ws_size,
                              hipStream_t stream) {
  const float* x    = (const float*)d_in[0];
  const int*   edge = (const int*)d_in[1];   // [2, n] flat: first n = row, next n = col
  const float* W    = (const float*)d_in[2];
  const float* bias = (const float*)d_in[3];
  float* out = (float*)d_out;

  const int n = in_sizes[0] / C;             // 500000

  int* deg = (int*)d_ws;
  size_t wb_off = ((size_t)n * sizeof(int) + 255) & ~(size_t)255;
  __bf16* Wb = (__bf16*)((char*)d_ws + wb_off);

  hipMemsetAsync(deg, 0, (size_t)n * sizeof(int), stream);

  int nb = (n + 255) / 256;
  prep_kernel<<<nb, 256, 0, stream>>>(edge, W, deg, Wb, n);

  int mb = (n + BROWS - 1) / BROWS;          // 3907 blocks, one 128-row slab each
  gconv_kernel<<<mb, 512, 0, stream>>>(x, edge + n, Wb, bias, deg, out, n);
}

// Round 5
// 508.437 us; speedup vs baseline: 1.0141x; 1.0141x over previous
//
#include <hip/hip_runtime.h>
#include <hip/hip_bf16.h>
#include <stdint.h>

typedef __attribute__((ext_vector_type(8))) __bf16 bf16x8;
typedef __attribute__((ext_vector_type(4))) float floatx4;

#define C 128
#define BROWS 64

__device__ __forceinline__ __bf16 f2b(float f) {
  return __builtin_bit_cast(__bf16, __float2bfloat16(f));
}

// histogram of row indices + W fp32 -> bf16 conversion
__global__ void prep_kernel(const int* __restrict__ rowidx, const float* __restrict__ W,
                            int* __restrict__ deg, __bf16* __restrict__ Wb, int n) {
  int i = blockIdx.x * blockDim.x + threadIdx.x;
  if (i < C * C) Wb[i] = f2b(W[i]);
  if (i < n) atomicAdd(deg + rowidx[i], 1);
}

// result[j] = (x[j] + x[col[j]]) @ W.T + 2*b + deg[j]
// ONE-SHOT blocks in hardware dispatch order (R3-verified: keeps gathers
// L3-resident, FETCH/WRITE at the 512MB floor).
// R5: (a) sW shrunk 34.8KB -> 32KB via XOR-swizzled 16B slots => 5 blocks/CU;
//     (b) launch_bounds(256,5) (VGPR cap 102; R4's (512,8) cap of 64 caused
//         spills, VGPR_Count=32);
//     (c) sched_barrier(0) pins all 16 A-loads before the barrier so the
//         full burst stays in flight (R3 compiler sank them into the loop).
__launch_bounds__(256, 5)
__global__ void gconv_kernel(const float* __restrict__ x,
                             const int* __restrict__ colidx,
                             const __bf16* __restrict__ Wb,
                             const float* __restrict__ bias,
                             const int* __restrict__ deg,
                             float* __restrict__ out, int n) {
  __shared__ bf16x8 sW[2048];   // 32768 B: row r = slots [r*16, r*16+16), slot ^= (r&15)

  const int t = threadIdx.x;
  const int lane = t & 63, w = t >> 6;
  const int l15 = lane & 15, quad = lane >> 4;

  const int base = blockIdx.x * BROWS + w * 16;

  // index load first: its latency hides under W staging
  int ga  = base + l15;
  int gal = ga < n ? ga : n - 1;
  int cg  = colidx[gal];

  // ---- stage W: thread t covers row r=t>>1, half h=t&1 (8 x 16B slots) ----
  // loads issue now; regs are freed by the ds_writes before the A-burst peaks
  {
    int r = t >> 1, h = t & 1, rx = r & 15;
    const bf16x8* src = (const bf16x8*)(Wb + r * C) + h * 8;
    bf16x8 wreg[8];
#pragma unroll
    for (int i = 0; i < 8; i++) wreg[i] = src[i];
#pragma unroll
    for (int i = 0; i < 8; i++) sW[r * 16 + ((h * 8 + i) ^ rx)] = wreg[i];
  }

  // ---- A-side burst: 16 float4 loads per lane, straight from global ----
  // lane (l15, quad) owns row base+l15, k = quad*8 + kc*32 + j
  const float4* pa = (const float4*)(x + (size_t)gal * C + quad * 8);
  float4 va[8];
#pragma unroll
  for (int kc = 0; kc < 4; kc++) {
    va[2 * kc]     = pa[kc * 8];
    va[2 * kc + 1] = pa[kc * 8 + 1];
  }
  const float4* pc = (const float4*)(x + (size_t)cg * C + quad * 8);
  float4 vc[8];
#pragma unroll
  for (int kc = 0; kc < 4; kc++) {
    vc[2 * kc]     = pc[kc * 8];
    vc[2 * kc + 1] = pc[kc * 8 + 1];
  }

  // deg for the 4 epilogue rows of this lane (row = base + quad*4 + r)
  int gr  = base + quad * 4;
  int grl = (gr + 3 < n) ? gr : ((n - 4) & ~3);
  int4 d4 = *(const int4*)(deg + grl);

  // per-lane bias (col = tt*16 + l15)
  float b2[8];
#pragma unroll
  for (int tt = 0; tt < 8; tt++) b2[tt] = 2.0f * bias[tt * 16 + l15];

  __builtin_amdgcn_sched_barrier(0);   // keep every load above issued up here
  __syncthreads();

  // ---- convert A fragments (frees va/vc) ----
  bf16x8 av[4];
#pragma unroll
  for (int kc = 0; kc < 4; kc++) {
    float4 a0 = va[2 * kc], a1 = va[2 * kc + 1];
    float4 c0 = vc[2 * kc], c1 = vc[2 * kc + 1];
    av[kc][0] = f2b(a0.x + c0.x); av[kc][1] = f2b(a0.y + c0.y);
    av[kc][2] = f2b(a0.z + c0.z); av[kc][3] = f2b(a0.w + c0.w);
    av[kc][4] = f2b(a1.x + c1.x); av[kc][5] = f2b(a1.y + c1.y);
    av[kc][6] = f2b(a1.z + c1.z); av[kc][7] = f2b(a1.w + c1.w);
  }

  // B frag (kc,tt): row nrow = tt*16+l15, 16B-slot (quad+kc*4) ^ (nrow&15)
  int sx0 = (quad + 0)  ^ l15;
  int sx1 = (quad + 4)  ^ l15;
  int sx2 = (quad + 8)  ^ l15;
  int sx3 = (quad + 12) ^ l15;

  floatx4 acc[8];
#pragma unroll
  for (int i = 0; i < 8; i++) acc[i] = (floatx4){0.f, 0.f, 0.f, 0.f};

  const bf16x8* wr0 = sW + l15 * 16 + sx0;
  const bf16x8* wr1 = sW + l15 * 16 + sx1;
  const bf16x8* wr2 = sW + l15 * 16 + sx2;
  const bf16x8* wr3 = sW + l15 * 16 + sx3;
#pragma unroll
  for (int tt = 0; tt < 8; tt++) {
    acc[tt] = __builtin_amdgcn_mfma_f32_16x16x32_bf16(av[0], wr0[tt * 256], acc[tt], 0, 0, 0);
    acc[tt] = __builtin_amdgcn_mfma_f32_16x16x32_bf16(av[1], wr1[tt * 256], acc[tt], 0, 0, 0);
    acc[tt] = __builtin_amdgcn_mfma_f32_16x16x32_bf16(av[2], wr2[tt * 256], acc[tt], 0, 0, 0);
    acc[tt] = __builtin_amdgcn_mfma_f32_16x16x32_bf16(av[3], wr3[tt * 256], acc[tt], 0, 0, 0);
  }

  // ---- epilogue: C/D layout col=l15, row=quad*4+reg (HW-verified) ----
  float dvf[4];
  dvf[0] = (float)d4.x; dvf[1] = (float)d4.y;
  dvf[2] = (float)d4.z; dvf[3] = (float)d4.w;
#pragma unroll
  for (int r = 0; r < 4; r++) {
    int g = gr + r;
    if (g < n) {
      float* orow = out + (size_t)g * C + l15;
      float dv = dvf[r];
#pragma unroll
      for (int tt = 0; tt < 8; tt++) orow[tt * 16] = acc[tt][r] + b2[tt] + dv;
    }
  }
}

extern "C" void kernel_launch(void* const* d_in, const int* in_sizes, int n_in,
                              void* d_out, int out_size, void* d_ws, size_t ws_size,
                              hipStream_t stream) {
  const float* x    = (const float*)d_in[0];
  const int*   edge = (const int*)d_in[1];   // [2, n] flat: first n = row, next n = col
  const float* W    = (const float*)d_in[2];
  const float* bias = (const float*)d_in[3];
  float* out = (float*)d_out;

  const int n = in_sizes[0] / C;             // 500000

  int* deg = (int*)d_ws;
  size_t wb_off = ((size_t)n * sizeof(int) + 255) & ~(size_t)255;
  __bf16* Wb = (__bf16*)((char*)d_ws + wb_off);

  hipMemsetAsync(deg, 0, (size_t)n * sizeof(int), stream);

  int nb = (n + 255) / 256;
  prep_kernel<<<nb, 256, 0, stream>>>(edge, W, deg, Wb, n);

  int mb = (n + BROWS - 1) / BROWS;          // 7813 blocks, one 64-row tile each
  gconv_kernel<<<mb, 256, 0, stream>>>(x, edge + n, Wb, bias, deg, out, n);
}

// Round 6
// 504.139 us; speedup vs baseline: 1.0228x; 1.0085x over previous
//
#include <hip/hip_runtime.h>
#include <hip/hip_bf16.h>
#include <stdint.h>

typedef __attribute__((ext_vector_type(8))) __bf16 bf16x8;
typedef __attribute__((ext_vector_type(4))) float floatx4;

#define C 128
#define BROWS 64

__device__ __forceinline__ __bf16 f2b(float f) {
  return __builtin_bit_cast(__bf16, __float2bfloat16(f));
}

// histogram of row indices + W fp32 -> bf16 conversion
__global__ void prep_kernel(const int* __restrict__ rowidx, const float* __restrict__ W,
                            int* __restrict__ deg, __bf16* __restrict__ Wb, int n) {
  int i = blockIdx.x * blockDim.x + threadIdx.x;
  if (i < C * C) Wb[i] = f2b(W[i]);
  if (i < n) atomicAdd(deg + rowidx[i], 1);
}

// result[j] = (x[j] + x[col[j]]) @ W.T + 2*b + deg[j]
// ONE-SHOT blocks in hardware dispatch order (R3-verified: keeps gathers
// L3-resident, FETCH/WRITE at the 512MB floor).
// R6: force full 16-load burst per lane to stay in flight. R4 (spills) and
// R5 (VGPR=48 -> compiler sank loads past sched_barrier) both failed to
// actually run this experiment. A single asm volatile with ALL 16 results
// as "+v" operands creates a data dependency: issue 16, drain once.
// launch_bounds(256,4) -> VGPR cap 128 (peak live ~120, no spill).
__launch_bounds__(256, 4)
__global__ void gconv_kernel(const float* __restrict__ x,
                             const int* __restrict__ colidx,
                             const __bf16* __restrict__ Wb,
                             const float* __restrict__ bias,
                             const int* __restrict__ deg,
                             float* __restrict__ out, int n) {
  __shared__ bf16x8 sW[2048];   // 32768 B: row r = slots [r*16, r*16+16), slot ^= (r&15)

  const int t = threadIdx.x;
  const int lane = t & 63, w = t >> 6;
  const int l15 = lane & 15, quad = lane >> 4;

  const int base = blockIdx.x * BROWS + w * 16;

  // index load first: its latency hides under W staging
  int ga  = base + l15;
  int gal = ga < n ? ga : n - 1;
  int cg  = colidx[gal];

  // ---- stage W: thread t covers row r=t>>1, half h=t&1 (8 x 16B slots) ----
  {
    int r = t >> 1, h = t & 1, rx = r & 15;
    const bf16x8* src = (const bf16x8*)(Wb + r * C) + h * 8;
    bf16x8 wreg[8];
#pragma unroll
    for (int i = 0; i < 8; i++) wreg[i] = src[i];
#pragma unroll
    for (int i = 0; i < 8; i++) sW[r * 16 + ((h * 8 + i) ^ rx)] = wreg[i];
  }

  // ---- A-side burst: 16 float4 loads per lane, straight from global ----
  // lane (l15, quad) owns row base+l15, k = quad*8 + kc*32 + j
  const floatx4* pa = (const floatx4*)(x + (size_t)gal * C) + quad * 2;
  const floatx4* pc = (const floatx4*)(x + (size_t)cg  * C) + quad * 2;
  floatx4 va[8], vc[8];
#pragma unroll
  for (int kc = 0; kc < 4; kc++) {
    va[2 * kc]     = pa[kc * 8];
    va[2 * kc + 1] = pa[kc * 8 + 1];
    vc[2 * kc]     = pc[kc * 8];
    vc[2 * kc + 1] = pc[kc * 8 + 1];
  }

  // deg for the 4 epilogue rows of this lane (row = base + quad*4 + r)
  int gr  = base + quad * 4;
  int grl = (gr + 3 < n) ? gr : ((n - 4) & ~3);
  int4 d4 = *(const int4*)(deg + grl);

  // per-lane bias (col = tt*16 + l15)
  float b2[8];
#pragma unroll
  for (int tt = 0; tt < 8; tt++) b2[tt] = 2.0f * bias[tt * 16 + l15];

  __syncthreads();

  // ---- PIN: all 16 A-loads must be issued and live HERE, simultaneously ----
  // (data dependency -- cannot be sunk or interleaved with the converts)
  asm volatile("" : "+v"(va[0]), "+v"(va[1]), "+v"(va[2]), "+v"(va[3]),
                    "+v"(va[4]), "+v"(va[5]), "+v"(va[6]), "+v"(va[7]),
                    "+v"(vc[0]), "+v"(vc[1]), "+v"(vc[2]), "+v"(vc[3]),
                    "+v"(vc[4]), "+v"(vc[5]), "+v"(vc[6]), "+v"(vc[7]));

  // ---- convert A fragments (frees va/vc) ----
  bf16x8 av[4];
#pragma unroll
  for (int kc = 0; kc < 4; kc++) {
    floatx4 a0 = va[2 * kc], a1 = va[2 * kc + 1];
    floatx4 c0 = vc[2 * kc], c1 = vc[2 * kc + 1];
    av[kc][0] = f2b(a0[0] + c0[0]); av[kc][1] = f2b(a0[1] + c0[1]);
    av[kc][2] = f2b(a0[2] + c0[2]); av[kc][3] = f2b(a0[3] + c0[3]);
    av[kc][4] = f2b(a1[0] + c1[0]); av[kc][5] = f2b(a1[1] + c1[1]);
    av[kc][6] = f2b(a1[2] + c1[2]); av[kc][7] = f2b(a1[3] + c1[3]);
  }

  // B frag (kc,tt): row nrow = tt*16+l15, 16B-slot (quad+kc*4) ^ (nrow&15)
  int sx0 = (quad + 0)  ^ l15;
  int sx1 = (quad + 4)  ^ l15;
  int sx2 = (quad + 8)  ^ l15;
  int sx3 = (quad + 12) ^ l15;

  floatx4 acc[8];
#pragma unroll
  for (int i = 0; i < 8; i++) acc[i] = (floatx4){0.f, 0.f, 0.f, 0.f};

  const bf16x8* wr0 = sW + l15 * 16 + sx0;
  const bf16x8* wr1 = sW + l15 * 16 + sx1;
  const bf16x8* wr2 = sW + l15 * 16 + sx2;
  const bf16x8* wr3 = sW + l15 * 16 + sx3;
#pragma unroll
  for (int tt = 0; tt < 8; tt++) {
    acc[tt] = __builtin_amdgcn_mfma_f32_16x16x32_bf16(av[0], wr0[tt * 256], acc[tt], 0, 0, 0);
    acc[tt] = __builtin_amdgcn_mfma_f32_16x16x32_bf16(av[1], wr1[tt * 256], acc[tt], 0, 0, 0);
    acc[tt] = __builtin_amdgcn_mfma_f32_16x16x32_bf16(av[2], wr2[tt * 256], acc[tt], 0, 0, 0);
    acc[tt] = __builtin_amdgcn_mfma_f32_16x16x32_bf16(av[3], wr3[tt * 256], acc[tt], 0, 0, 0);
  }

  // ---- epilogue: C/D layout col=l15, row=quad*4+reg (HW-verified) ----
  float dvf[4];
  dvf[0] = (float)d4.x; dvf[1] = (float)d4.y;
  dvf[2] = (float)d4.z; dvf[3] = (float)d4.w;
#pragma unroll
  for (int r = 0; r < 4; r++) {
    int g = gr + r;
    if (g < n) {
      float* orow = out + (size_t)g * C + l15;
      float dv = dvf[r];
#pragma unroll
      for (int tt = 0; tt < 8; tt++) orow[tt * 16] = acc[tt][r] + b2[tt] + dv;
    }
  }
}

extern "C" void kernel_launch(void* const* d_in, const int* in_sizes, int n_in,
                              void* d_out, int out_size, void* d_ws, size_t ws_size,
                              hipStream_t stream) {
  const float* x    = (const float*)d_in[0];
  const int*   edge = (const int*)d_in[1];   // [2, n] flat: first n = row, next n = col
  const float* W    = (const float*)d_in[2];
  const float* bias = (const float*)d_in[3];
  float* out = (float*)d_out;

  const int n = in_sizes[0] / C;             // 500000

  int* deg = (int*)d_ws;
  size_t wb_off = ((size_t)n * sizeof(int) + 255) & ~(size_t)255;
  __bf16* Wb = (__bf16*)((char*)d_ws + wb_off);

  hipMemsetAsync(deg, 0, (size_t)n * sizeof(int), stream);

  int nb = (n + 255) / 256;
  prep_kernel<<<nb, 256, 0, stream>>>(edge, W, deg, Wb, n);

  int mb = (n + BROWS - 1) / BROWS;          // 7813 blocks, one 64-row tile each
  gconv_kernel<<<mb, 256, 0, stream>>>(x, edge + n, Wb, bias, deg, out, n);
}